// Round 18
// baseline (69.884 us; speedup 1.0000x reference)
//
#include <hip/hip_runtime.h>
#include <cstddef>

#define BB  32
#define CC  128
#define HH  64
#define WW  64
#define OO  256
#define OHH 32
#define OWW 32
#define YSTR 196            // yr row stride (bf16 elems)
#define ROWE (32 * YSTR)    // 6272 elems per yr p-row
#define PSTR 296            // pT row stride; 592B rows, 16B-aligned
#define PTSLOT (64 * PSTR)  // one pT slot (64 n-rows)

typedef __bf16 bf16x8 __attribute__((ext_vector_type(8)));
typedef __bf16 bf16x4 __attribute__((ext_vector_type(4)));
typedef float  f32x4  __attribute__((ext_vector_type(4)));

// ---- weight transform: w[o][c][3][3] f32 -> wt[o][k][c] bf16 (k = kh*3+kw) ----
__global__ void wtrans_bf16_kernel(const float* __restrict__ w, __bf16* __restrict__ wt) {
    int idx = blockIdx.x * 256 + threadIdx.x;          // (o*9 + k)*128 + c
    if (idx >= OO * 9 * CC) return;
    int c    = idx & 127;
    int rest = idx >> 7;
    int k    = rest % 9;
    int o    = rest / 9;
    wt[idx] = (__bf16)w[((size_t)o * CC + c) * 9 + k];
}

// ---- fused bilinear-im2col + bf16 MFMA, producer-consumer wave split ----
// grid (b=32, pp=16) = 512 blocks; 512 thr = 8 waves; ~101KB LDS, 1 block/CU.
// Waves 0-3 PRODUCE (stage A -> yr; stage B -> pT slots, double-buffered).
// Waves 4-7 CONSUME (MFMA, 64o x 64n each). Sync = LDS flag counters
// (release-fence + atomicAdd per wave; acquire poll) -- no lockstep barriers,
// so producer VALU/LDS and consumer MFMA/L2 overlap across waves.
__global__ __launch_bounds__(512, 2)
void conv_mfma_kernel(const float* __restrict__ x, const __bf16* __restrict__ wt,
                      const float* __restrict__ bias, const float* __restrict__ shp,
                      const float* __restrict__ swp, float* __restrict__ out) {
    __shared__ __align__(16) __bf16 yrbuf[4 + 2 * ROWE];   // 2 p-rows + front pad
    __shared__ __align__(16) __bf16 pT[2 * PTSLOT];        // 2 slots x 64 n-rows
    __shared__ int ydone, pdone, cdone;

    const int tid = threadIdx.x;
    const int b   = blockIdx.x;
    const int p0  = blockIdx.y * 2;
    const float sh = shp[0];
    const float sw = swp[0];

    float fh_[2];
    int   hb_[2];
#pragma unroll
    for (int pi = 0; pi < 2; ++pi) {
        float hpos = (float)(p0 + pi) * sh - 1.0f;
        float hbf  = floorf(hpos);
        fh_[pi] = hpos - hbf;
        hb_[pi] = (int)hbf;
    }
    const bool oob0 = (hb_[0] >= HH || hb_[0] <= -4);
    const bool oob1 = (hb_[1] >= HH || hb_[1] <= -4);

    // ---- bias-only fast path: both rows fully OOB ----
    if (oob0 && oob1) {
#pragma unroll
        for (int j = 0; j < 8; ++j) {
            int fi = j * 512 + tid;        // 4096 float4 = 256 o x 2 p x 8
            int o  = fi >> 4;
            int rem = fi & 15;
            int pi = rem >> 3;
            int qf = rem & 7;
            float bv = bias[o];
            float4 r; r.x = bv; r.y = bv; r.z = bv; r.w = bv;
            *(float4*)(out + (((size_t)b * OO + o) * OHH + p0 + pi) * OWW + qf * 4) = r;
        }
        return;
    }

    if (tid == 0) { ydone = 0; pdone = 0; cdone = 0; }
    if (tid < 4) yrbuf[tid] = (__bf16)0.0f;   // zero front pad
    __syncthreads();   // the ONLY full barrier

    const int wv = tid >> 6;
    const int l  = tid & 63;
    const int lr = l & 15;
    const int lg = l >> 4;

    // flag helpers: all lanes poll (uniform), lane0 posts
    auto waitge = [&](int* f, int t) {
        while (__hip_atomic_load(f, __ATOMIC_RELAXED, __HIP_MEMORY_SCOPE_WORKGROUP) < t)
            __builtin_amdgcn_s_sleep(2);
        __threadfence_block();                 // acquire: order later LDS reads
        __builtin_amdgcn_sched_barrier(0);     // rule-18 insurance
    };
    auto post = [&](int* f) {
        __threadfence_block();                 // release: drain LDS writes
        if ((tid & 63) == 0)
            __hip_atomic_fetch_add(f, 1, __ATOMIC_RELAXED, __HIP_MEMORY_SCOPE_WORKGROUP);
    };

    if (wv < 4) {
        // ================= PRODUCER waves (tid 0..255) =================
        // stage-A ownership: (pi, c, 16-col group)
        const int piA = tid >> 7;             // 0..1
        const int t7  = tid & 127;
        const int cA  = t7 >> 2;              // 0..31
        const int cg0 = (t7 & 3) * 16;
        const float fhA = fh_[piA];
        int  hrA[4];
        bool rvA[4];
#pragma unroll
        for (int r = 0; r < 4; ++r) {
            hrA[r] = hb_[piA] + r;
            rvA[r] = (hrA[r] >= 0) && (hrA[r] < HH);
        }
        __bf16* yrA = yrbuf + 4 + piA * ROWE;

        // stage-B ownership: (n-row 0..63, 8 channels in 2 groups of 4)
        const int qB2  = tid >> 2;            // 0..63
        const int pi2B = qB2 >> 5;
        const int qB   = qB2 & 31;
        const int cB   = (tid & 3) * 8;
        const float wposB = (float)qB * sw - 1.0f;
        const float wbfB  = floorf(wposB);
        const float fw    = wposB - wbfB;
        const int   wbq   = (int)wbfB;
        const int   wba   = min(wbq & ~3, 60);
        const int   e     = wbq - wba;
        const bool  g1 = e >= 1, g2 = e >= 2, g3 = e >= 3;
        bool mv[4];
#pragma unroll
        for (int j = 0; j < 4; ++j) mv[j] = ((unsigned)(wbq + j) < (unsigned)WW);
        const bool qDead = (wbq >= WW);
        const __bf16* yrB = yrbuf + 4 + pi2B * ROWE;

        // dead-q rows: zero once in BOTH slots (before any pdone post)
        if (qDead) {
            bf16x4 z;
            z[0] = (__bf16)0.0f; z[1] = (__bf16)0.0f; z[2] = (__bf16)0.0f; z[3] = (__bf16)0.0f;
#pragma unroll
            for (int s = 0; s < 2; ++s) {
                __bf16* pq = pT + s * PTSLOT + qB2 * PSTR;
#pragma unroll
                for (int kk = 0; kk < 9; ++kk) {
                    *(bf16x4*)(pq + kk * 32 + cB)     = z;
                    *(bf16x4*)(pq + kk * 32 + cB + 4) = z;
                }
            }
        }

        for (int c = 0; c < 4; ++c) {
            const int c0 = c * 32;
            if (c >= 1) waitge(&pdone, 4 * c);          // yr free (all B(c-1) done)

            // ---- stage A: load x rows, row-interp, write yr ----
            {
                const float* xp = x + ((size_t)(b * CC + c0 + cA) * HH) * WW;
                float4 v[4][4];
#pragma unroll
                for (int r = 0; r < 4; ++r) {
                    if (rvA[r]) {
                        const float* rp = xp + (size_t)hrA[r] * WW + cg0;
#pragma unroll
                        for (int g = 0; g < 4; ++g) v[r][g] = *(const float4*)(rp + g * 4);
                    } else {
#pragma unroll
                        for (int g = 0; g < 4; ++g) { v[r][g].x = 0.f; v[r][g].y = 0.f; v[r][g].z = 0.f; v[r][g].w = 0.f; }
                    }
                }
                __bf16* yw = yrA + cA * YSTR + cg0;
#pragma unroll
                for (int kh = 0; kh < 3; ++kh)
#pragma unroll
                    for (int g = 0; g < 4; ++g) {
                        bf16x4 t;
                        t[0] = (__bf16)(v[kh][g].x + fhA * (v[kh + 1][g].x - v[kh][g].x));
                        t[1] = (__bf16)(v[kh][g].y + fhA * (v[kh + 1][g].y - v[kh][g].y));
                        t[2] = (__bf16)(v[kh][g].z + fhA * (v[kh + 1][g].z - v[kh][g].z));
                        t[3] = (__bf16)(v[kh][g].w + fhA * (v[kh + 1][g].w - v[kh][g].w));
                        *(bf16x4*)(yw + kh * 64 + g * 4) = t;
                    }
            }
            post(&ydone);
            waitge(&ydone, 4 * (c + 1));                 // all yr(c) written
            if (c >= 2) waitge(&cdone, 4 * (c - 1));     // pT slot consumed

            // ---- stage B: col-interp yr -> pT[c&1] (hoisted reads) ----
            if (!qDead) {
                __bf16* pqRow = pT + (c & 1) * PTSLOT + qB2 * PSTR;
#pragma unroll
                for (int g = 0; g < 2; ++g) {
                    const int cc0 = cB + g * 4;
                    bf16x4 rlo[12], rhi[12];
#pragma unroll
                    for (int ci = 0; ci < 4; ++ci)
#pragma unroll
                        for (int kh = 0; kh < 3; ++kh) {
                            const __bf16* yc = yrB + (cc0 + ci) * YSTR + kh * 64 + wba;
                            rlo[ci * 3 + kh] = *(const bf16x4*)yc;
                            rhi[ci * 3 + kh] = *(const bf16x4*)(yc + 4);
                        }
                    float tv[3][3][4];
#pragma unroll
                    for (int ci = 0; ci < 4; ++ci)
#pragma unroll
                        for (int kh = 0; kh < 3; ++kh) {
                            bf16x4 a  = rlo[ci * 3 + kh];
                            bf16x4 bq = rhi[ci * 3 + kh];
                            float v0 = (float)a[0], v1 = (float)a[1], v2 = (float)a[2], v3 = (float)a[3];
                            float v4 = (float)bq[0], v5 = (float)bq[1], v6 = (float)bq[2];
                            float s0 = g1 ? v1 : v0; s0 = g2 ? v2 : s0; s0 = g3 ? v3 : s0;
                            float s1 = g1 ? v2 : v1; s1 = g2 ? v3 : s1; s1 = g3 ? v4 : s1;
                            float s2 = g1 ? v3 : v2; s2 = g2 ? v4 : s2; s2 = g3 ? v5 : s2;
                            float s3 = g1 ? v4 : v3; s3 = g2 ? v5 : s3; s3 = g3 ? v6 : s3;
                            s0 = mv[0] ? s0 : 0.0f;
                            s1 = mv[1] ? s1 : 0.0f;
                            s2 = mv[2] ? s2 : 0.0f;
                            s3 = mv[3] ? s3 : 0.0f;
                            tv[kh][0][ci] = s0 + fw * (s1 - s0);
                            tv[kh][1][ci] = s1 + fw * (s2 - s1);
                            tv[kh][2][ci] = s2 + fw * (s3 - s2);
                        }
#pragma unroll
                    for (int kh = 0; kh < 3; ++kh)
#pragma unroll
                        for (int kw = 0; kw < 3; ++kw) {
                            bf16x4 pr;
                            pr[0] = (__bf16)tv[kh][kw][0];
                            pr[1] = (__bf16)tv[kh][kw][1];
                            pr[2] = (__bf16)tv[kh][kw][2];
                            pr[3] = (__bf16)tv[kh][kw][3];
                            *(bf16x4*)(pqRow + (kh * 3 + kw) * 32 + cc0) = pr;
                        }
                }
            }
            post(&pdone);
        }
        return;   // producers exit; consumers hold the epilogue
    }

    // ================= CONSUMER waves (wv 4..7) =================
    const int o0 = (wv - 4) * 64;
    f32x4 acc[4][4];
#pragma unroll
    for (int ot = 0; ot < 4; ++ot)
#pragma unroll
        for (int nt = 0; nt < 4; ++nt) acc[ot][nt] = (f32x4)0.0f;

#pragma unroll
    for (int c = 0; c < 4; ++c) {
        const int c0 = c * 32;
        waitge(&pdone, 4 * (c + 1));                     // pT[c&1] ready
        const __bf16* pTs = pT + (c & 1) * PTSLOT;
        __builtin_amdgcn_s_setprio(1);
#pragma unroll
        for (int k = 0; k < 9; ++k) {
            const __bf16* wp = wt + ((size_t)(o0 + lr) * 9 + k) * CC + c0 + lg * 8;
            bf16x8 a0 = *(const bf16x8*)(wp);
            bf16x8 a1 = *(const bf16x8*)(wp + (size_t)16 * 9 * CC);
            bf16x8 a2 = *(const bf16x8*)(wp + (size_t)32 * 9 * CC);
            bf16x8 a3 = *(const bf16x8*)(wp + (size_t)48 * 9 * CC);
            bf16x8 b0 = *(const bf16x8*)&pTs[(0  + lr) * PSTR + k * 32 + lg * 8];
            bf16x8 b1 = *(const bf16x8*)&pTs[(16 + lr) * PSTR + k * 32 + lg * 8];
            bf16x8 b2 = *(const bf16x8*)&pTs[(32 + lr) * PSTR + k * 32 + lg * 8];
            bf16x8 b3 = *(const bf16x8*)&pTs[(48 + lr) * PSTR + k * 32 + lg * 8];
            acc[0][0] = __builtin_amdgcn_mfma_f32_16x16x32_bf16(a0, b0, acc[0][0], 0, 0, 0);
            acc[0][1] = __builtin_amdgcn_mfma_f32_16x16x32_bf16(a0, b1, acc[0][1], 0, 0, 0);
            acc[0][2] = __builtin_amdgcn_mfma_f32_16x16x32_bf16(a0, b2, acc[0][2], 0, 0, 0);
            acc[0][3] = __builtin_amdgcn_mfma_f32_16x16x32_bf16(a0, b3, acc[0][3], 0, 0, 0);
            acc[1][0] = __builtin_amdgcn_mfma_f32_16x16x32_bf16(a1, b0, acc[1][0], 0, 0, 0);
            acc[1][1] = __builtin_amdgcn_mfma_f32_16x16x32_bf16(a1, b1, acc[1][1], 0, 0, 0);
            acc[1][2] = __builtin_amdgcn_mfma_f32_16x16x32_bf16(a1, b2, acc[1][2], 0, 0, 0);
            acc[1][3] = __builtin_amdgcn_mfma_f32_16x16x32_bf16(a1, b3, acc[1][3], 0, 0, 0);
            acc[2][0] = __builtin_amdgcn_mfma_f32_16x16x32_bf16(a2, b0, acc[2][0], 0, 0, 0);
            acc[2][1] = __builtin_amdgcn_mfma_f32_16x16x32_bf16(a2, b1, acc[2][1], 0, 0, 0);
            acc[2][2] = __builtin_amdgcn_mfma_f32_16x16x32_bf16(a2, b2, acc[2][2], 0, 0, 0);
            acc[2][3] = __builtin_amdgcn_mfma_f32_16x16x32_bf16(a2, b3, acc[2][3], 0, 0, 0);
            acc[3][0] = __builtin_amdgcn_mfma_f32_16x16x32_bf16(a3, b0, acc[3][0], 0, 0, 0);
            acc[3][1] = __builtin_amdgcn_mfma_f32_16x16x32_bf16(a3, b1, acc[3][1], 0, 0, 0);
            acc[3][2] = __builtin_amdgcn_mfma_f32_16x16x32_bf16(a3, b2, acc[3][2], 0, 0, 0);
            acc[3][3] = __builtin_amdgcn_mfma_f32_16x16x32_bf16(a3, b3, acc[3][3], 0, 0, 0);
        }
        __builtin_amdgcn_s_setprio(0);
        post(&cdone);
    }

    // ---- epilogue: + bias, store (C/D: col=lane&15, row=(lane>>4)*4+reg) ----
#pragma unroll
    for (int ot = 0; ot < 4; ++ot) {
#pragma unroll
        for (int r = 0; r < 4; ++r) {
            int o = o0 + ot * 16 + lg * 4 + r;
            float bv = bias[o];
#pragma unroll
            for (int nt = 0; nt < 4; ++nt) {
                int n  = nt * 16 + lr;
                int pi = n >> 5;
                int q  = n & 31;
                out[(((size_t)b * OO + o) * OHH + p0 + pi) * OWW + q] = acc[ot][nt][r] + bv;
            }
        }
    }
}

// ---- fp32 fallback (no workspace) ----
__global__ __launch_bounds__(256)
void conv_fallback_kernel(const float* __restrict__ x, const float* __restrict__ w,
                          const float* __restrict__ bias, const float* __restrict__ shp,
                          const float* __restrict__ swp, float* __restrict__ out) {
    __shared__ __align__(16) float xr[4][WW];
    __shared__ __align__(16) float patch[9][OWW];
    const int tid = threadIdx.x;
    const int p = blockIdx.y;
    const int b = blockIdx.x;
    const float sh = shp[0];
    const float sw = swp[0];
    const float hpos = (float)p * sh - 1.0f;
    const float hbf  = floorf(hpos);
    const float fh   = hpos - hbf;
    const int   hb   = (int)hbf;
    const int og = tid & 63;
    const int qg = tid >> 6;
    const int o0 = og * 4;
    const int q0 = qg * 8;
    const int rr   = tid >> 6;
    const int colc = tid & 63;
    const int rowg = hb + rr;
    const bool rv = (rowg >= 0) && (rowg < HH);
    float acc[4][8];
#pragma unroll
    for (int i = 0; i < 4; ++i)
#pragma unroll
        for (int j = 0; j < 8; ++j) acc[i][j] = 0.0f;
    for (int c = 0; c < CC; ++c) {
        float vv = 0.0f;
        if (rv) vv = x[(((size_t)b * CC + c) * HH + rowg) * WW + colc];
        xr[rr][colc] = vv;
        __syncthreads();
        for (int it = tid; it < 9 * OWW; it += 256) {
            int k = it >> 5; int q = it & 31;
            int kh = k / 3;  int kw = k - kh * 3;
            float wpos = (float)q * sw - 1.0f + (float)kw;
            float wbf = floorf(wpos);
            float fwl = wpos - wbf;
            int wb = (int)wbf;
            float x00 = 0, x01 = 0, x10 = 0, x11 = 0;
            if (wb >= 0 && wb < WW)         { x00 = xr[kh][wb];     x10 = xr[kh + 1][wb]; }
            if (wb + 1 >= 0 && wb + 1 < WW) { x01 = xr[kh][wb + 1]; x11 = xr[kh + 1][wb + 1]; }
            float top = x00 * (1.0f - fwl) + x01 * fwl;
            float bot = x10 * (1.0f - fwl) + x11 * fwl;
            patch[k][q] = top * (1.0f - fh) + bot * fh;
        }
        __syncthreads();
        const float4* pv = (const float4*)&patch[0][0];
#pragma unroll
        for (int k = 0; k < 9; ++k) {
            const float* wb_ = w + (size_t)o0 * (CC * 9) + c * 9 + k;
            float wvv[4] = {wb_[0], wb_[1 * CC * 9], wb_[2 * CC * 9], wb_[3 * CC * 9]};
            float4 pa = pv[k * 8 + (q0 >> 2)];
            float4 pb = pv[k * 8 + (q0 >> 2) + 1];
#pragma unroll
            for (int oo2 = 0; oo2 < 4; ++oo2) {
                acc[oo2][0] += wvv[oo2] * pa.x; acc[oo2][1] += wvv[oo2] * pa.y;
                acc[oo2][2] += wvv[oo2] * pa.z; acc[oo2][3] += wvv[oo2] * pa.w;
                acc[oo2][4] += wvv[oo2] * pb.x; acc[oo2][5] += wvv[oo2] * pb.y;
                acc[oo2][6] += wvv[oo2] * pb.z; acc[oo2][7] += wvv[oo2] * pb.w;
            }
        }
    }
    float4 bv = ((const float4*)bias)[og];
    float bvv[4] = {bv.x, bv.y, bv.z, bv.w};
#pragma unroll
    for (int oo2 = 0; oo2 < 4; ++oo2) {
        size_t off = (((size_t)b * OO + o0 + oo2) * OHH + p) * OWW + q0;
        float4 r0, r1;
        r0.x = acc[oo2][0] + bvv[oo2]; r0.y = acc[oo2][1] + bvv[oo2];
        r0.z = acc[oo2][2] + bvv[oo2]; r0.w = acc[oo2][3] + bvv[oo2];
        r1.x = acc[oo2][4] + bvv[oo2]; r1.y = acc[oo2][5] + bvv[oo2];
        r1.z = acc[oo2][6] + bvv[oo2]; r1.w = acc[oo2][7] + bvv[oo2];
        *(float4*)(out + off)     = r0;
        *(float4*)(out + off + 4) = r1;
    }
}

extern "C" void kernel_launch(void* const* d_in, const int* in_sizes, int n_in,
                              void* d_out, int out_size, void* d_ws, size_t ws_size,
                              hipStream_t stream) {
    const float* x    = (const float*)d_in[0];
    const float* w    = (const float*)d_in[1];
    const float* bias = (const float*)d_in[2];
    const float* shp  = (const float*)d_in[3];
    const float* swp  = (const float*)d_in[4];
    float* out = (float*)d_out;

    const size_t wt_bytes = (size_t)OO * 9 * CC * sizeof(__bf16);   // 576 KB
    if (ws_size >= wt_bytes) {
        __bf16* wtp = (__bf16*)d_ws;
        int n = OO * 9 * CC;
        wtrans_bf16_kernel<<<(n + 255) / 256, 256, 0, stream>>>(w, wtp);
        dim3 grid(BB, OHH / 2);
        conv_mfma_kernel<<<grid, 512, 0, stream>>>(x, wtp, bias, shp, swp, out);
    } else {
        dim3 grid(BB, OHH);
        conv_fallback_kernel<<<grid, 256, 0, stream>>>(x, w, bias, shp, swp, out);
    }
}

// Round 19
// 65.526 us; speedup vs baseline: 1.0665x; 1.0665x over previous
//
#include <hip/hip_runtime.h>
#include <cstddef>

#define BB  32
#define CC  128
#define HH  64
#define WW  64
#define OO  256
#define OHH 32
#define OWW 32
#define YSTR 196            // yr row stride (bf16 elems)
#define PSTR 296            // pT row stride; 592B rows, 16B-aligned
#define ROWE (32 * YSTR)    // 6272 elems per yr(p) buffer

typedef __bf16 bf16x8 __attribute__((ext_vector_type(8)));
typedef __bf16 bf16x4 __attribute__((ext_vector_type(4)));
typedef float  f32x4  __attribute__((ext_vector_type(4)));

// ---- weight transform: w[o][c][3][3] f32 -> wt[o][k][c] bf16 (k = kh*3+kw) ----
__global__ void wtrans_bf16_kernel(const float* __restrict__ w, __bf16* __restrict__ wt) {
    int idx = blockIdx.x * 256 + threadIdx.x;          // (o*9 + k)*128 + c
    if (idx >= OO * 9 * CC) return;
    int c    = idx & 127;
    int rest = idx >> 7;
    int k    = rest % 9;
    int o    = rest / 9;
    wt[idx] = (__bf16)w[((size_t)o * CC + c) * 9 + k];
}

// ---- fused bilinear-im2col + bf16 MFMA; block = (b, 4 p-rows), N=128 ----
// R19: barrier-aligned role asymmetry. Stage B = all 8 waves (512 thr).
// MFMA = waves 0-3 only, 64o x 128n each -> per-CU pT b128 reads HALVE
// (2304 -> 1152), no A redundancy (4 x 64o = 256o). Waves 4-7 run stage
// A(c+1) DURING the MFMA phase (yr is free after barB; audited hazard-clean).
// Lockstep barriers retained (R18 flag-polling regressed).
__global__ __launch_bounds__(512, 2)
void conv_mfma_kernel(const float* __restrict__ x, const __bf16* __restrict__ wt,
                      const float* __restrict__ bias, const float* __restrict__ shp,
                      const float* __restrict__ swp, float* __restrict__ out) {
    __shared__ __align__(16) __bf16 yrbuf[4 + 4 * ROWE];   // 4 p-rows + front pad
    __shared__ __align__(16) __bf16 pT[128 * PSTR];        // B operand: row = pi*32+q

    const int tid = threadIdx.x;
    const int b   = blockIdx.x;
    const int p0  = blockIdx.y * 4;
    const float sh = shp[0];
    const float sw = swp[0];

    // per-p row geometry (4 rows of this block)
    float fh_[4];
    int   hb_[4];
    bool  oob[4];
#pragma unroll
    for (int pi = 0; pi < 4; ++pi) {
        float hpos = (float)(p0 + pi) * sh - 1.0f;
        float hbf  = floorf(hpos);
        fh_[pi] = hpos - hbf;
        hb_[pi] = (int)hbf;
        oob[pi] = (hb_[pi] >= HH || hb_[pi] <= -4);
    }

    // ---- bias-only fast path: all 4 rows fully OOB ----
    if (oob[0] && oob[1] && oob[2] && oob[3]) {
#pragma unroll
        for (int j = 0; j < 16; ++j) {
            int fi = j * 512 + tid;        // 8192 float4 = 256 o x 4 p x 8
            int o  = fi >> 5;
            int rem = fi & 31;
            int pi = rem >> 3;
            int qf = rem & 7;
            float bv = bias[o];
            float4 r; r.x = bv; r.y = bv; r.z = bv; r.w = bv;
            *(float4*)(out + (((size_t)b * OO + o) * OHH + p0 + pi) * OWW + qf * 4) = r;
        }
        return;
    }
    // (mixed OOB rows fall through: masked loads -> zero patch -> bias)

    // ---- prologue stage-A ownership (all 512): 128 thr per p-row ----
    const int piA = tid >> 7;             // 0..3
    const int t7  = tid & 127;
    const int cA  = t7 >> 2;              // 0..31
    const int cg0 = (t7 & 3) * 16;        // col group start: 0,16,32,48
    const float fhA = fh_[piA];
    int  hrA[4];
    bool rvA[4];
#pragma unroll
    for (int r = 0; r < 4; ++r) {
        hrA[r] = hb_[piA] + r;
        rvA[r] = (hrA[r] >= 0) && (hrA[r] < HH);
    }
    __bf16* yrA = yrbuf + 4 + piA * ROWE;

    // ---- steady stage-A' ownership (waves 4-7, 256 thr): 64 thr per p-row ----
    const int t8   = tid & 255;
    const int piA2 = t8 >> 6;             // 0..3
    const int u6   = t8 & 63;
    const int cA2  = u6 >> 1;             // 0..31
    const int colh = (u6 & 1) * 32;       // half-row: 32 cols = 8 float4
    const float fhA2 = fh_[piA2];
    int  hrA2[4];
    bool rvA2[4];
#pragma unroll
    for (int r = 0; r < 4; ++r) {
        hrA2[r] = hb_[piA2] + r;
        rvA2[r] = (hrA2[r] >= 0) && (hrA2[r] < HH);
    }
    __bf16* yrA2 = yrbuf + 4 + piA2 * ROWE;

    // ---- stage-B ownership (all 512): (pi, q, 8 channels in 2 groups of 4) ----
    const int piB = tid >> 7;             // 0..3
    const int qB  = (tid >> 2) & 31;      // 0..31
    const int cB  = (tid & 3) * 8;        // 0,8,16,24
    const float wposB = (float)qB * sw - 1.0f;
    const float wbfB  = floorf(wposB);
    const float fw    = wposB - wbfB;
    const int   wbq   = (int)wbfB;
    const int   wba   = min(wbq & ~3, 60);
    const int   e     = wbq - wba;
    const bool  g1 = e >= 1, g2 = e >= 2, g3 = e >= 3;
    bool mv[4];
#pragma unroll
    for (int j = 0; j < 4; ++j) mv[j] = ((unsigned)(wbq + j) < (unsigned)WW);
    const __bf16* yrB = yrbuf + 4 + piB * ROWE;
    __bf16* pqRow = pT + (piB * 32 + qB) * PSTR;

    // ---- MFMA ownership: waves 0-3, 64 o x 128 n each ----
    const int wv = tid >> 6;
    const int l  = tid & 63;
    const int lr = l & 15;
    const int lg = l >> 4;
    const int o0 = (wv & 3) * 64;

    f32x4 acc[4][8];
#pragma unroll
    for (int ot = 0; ot < 4; ++ot)
#pragma unroll
        for (int nt = 0; nt < 8; ++nt) acc[ot][nt] = (f32x4)0.0f;

    if (tid < 4) yrbuf[tid] = (__bf16)0.0f;   // zero front pad

    // ---- prologue: stage A(0) with all 512 threads ----
    {
        const float* xp = x + ((size_t)(b * CC + cA) * HH) * WW;
        float4 v[4][4];   // [row][col4]
#pragma unroll
        for (int r = 0; r < 4; ++r) {
            if (rvA[r]) {
                const float* rp = xp + (size_t)hrA[r] * WW + cg0;
#pragma unroll
                for (int g = 0; g < 4; ++g) v[r][g] = *(const float4*)(rp + g * 4);
            } else {
#pragma unroll
                for (int g = 0; g < 4; ++g) { v[r][g].x = 0.f; v[r][g].y = 0.f; v[r][g].z = 0.f; v[r][g].w = 0.f; }
            }
        }
        __bf16* yw = yrA + cA * YSTR + cg0;
#pragma unroll
        for (int kh = 0; kh < 3; ++kh)
#pragma unroll
            for (int g = 0; g < 4; ++g) {
                bf16x4 t;
                t[0] = (__bf16)(v[kh][g].x + fhA * (v[kh + 1][g].x - v[kh][g].x));
                t[1] = (__bf16)(v[kh][g].y + fhA * (v[kh + 1][g].y - v[kh][g].y));
                t[2] = (__bf16)(v[kh][g].z + fhA * (v[kh + 1][g].z - v[kh][g].z));
                t[3] = (__bf16)(v[kh][g].w + fhA * (v[kh + 1][g].w - v[kh][g].w));
                *(bf16x4*)(yw + kh * 64 + g * 4) = t;
            }
    }
    __syncthreads();

    for (int chunk = 0; chunk < 4; ++chunk) {
        const int c0 = chunk * 32;

        // ---- stage B: col-interp yr -> pT (all 512 threads) ----
#pragma unroll
        for (int g = 0; g < 2; ++g) {
            const int cc0 = cB + g * 4;
            float tv[3][3][4];   // [kh][kw][ci]
#pragma unroll
            for (int ci = 0; ci < 4; ++ci) {
                const __bf16* yc = yrB + (cc0 + ci) * YSTR + wba;
#pragma unroll
                for (int kh = 0; kh < 3; ++kh) {
                    bf16x4 a  = *(const bf16x4*)(yc + kh * 64);
                    bf16x4 bq = *(const bf16x4*)(yc + kh * 64 + 4);
                    float v0 = (float)a[0], v1 = (float)a[1], v2 = (float)a[2], v3 = (float)a[3];
                    float v4 = (float)bq[0], v5 = (float)bq[1], v6 = (float)bq[2];
                    float s0 = g1 ? v1 : v0; s0 = g2 ? v2 : s0; s0 = g3 ? v3 : s0;
                    float s1 = g1 ? v2 : v1; s1 = g2 ? v3 : s1; s1 = g3 ? v4 : s1;
                    float s2 = g1 ? v3 : v2; s2 = g2 ? v4 : s2; s2 = g3 ? v5 : s2;
                    float s3 = g1 ? v4 : v3; s3 = g2 ? v5 : s3; s3 = g3 ? v6 : s3;
                    s0 = mv[0] ? s0 : 0.0f;
                    s1 = mv[1] ? s1 : 0.0f;
                    s2 = mv[2] ? s2 : 0.0f;
                    s3 = mv[3] ? s3 : 0.0f;
                    tv[kh][0][ci] = s0 + fw * (s1 - s0);
                    tv[kh][1][ci] = s1 + fw * (s2 - s1);
                    tv[kh][2][ci] = s2 + fw * (s3 - s2);
                }
            }
#pragma unroll
            for (int kh = 0; kh < 3; ++kh)
#pragma unroll
                for (int kw = 0; kw < 3; ++kw) {
                    bf16x4 pr;
                    pr[0] = (__bf16)tv[kh][kw][0];
                    pr[1] = (__bf16)tv[kh][kw][1];
                    pr[2] = (__bf16)tv[kh][kw][2];
                    pr[3] = (__bf16)tv[kh][kw][3];
                    *(bf16x4*)(pqRow + (kh * 3 + kw) * 32 + cc0) = pr;
                }
        }
        __syncthreads();   // barB: pT ready; yr reads drained (yr now free)

        if (wv < 4) {
            // ---- MFMA waves: 9 taps x (4 o-tiles x 8 n-tiles) ----
            __builtin_amdgcn_s_setprio(1);
#pragma unroll
            for (int k = 0; k < 9; ++k) {
                const __bf16* wp = wt + ((size_t)(o0 + lr) * 9 + k) * CC + c0 + lg * 8;
                bf16x8 a0 = *(const bf16x8*)(wp);
                bf16x8 a1 = *(const bf16x8*)(wp + (size_t)16 * 9 * CC);
                bf16x8 a2 = *(const bf16x8*)(wp + (size_t)32 * 9 * CC);
                bf16x8 a3 = *(const bf16x8*)(wp + (size_t)48 * 9 * CC);
                bf16x8 bfr[8];
#pragma unroll
                for (int nt = 0; nt < 8; ++nt)
                    bfr[nt] = *(const bf16x8*)&pT[(nt * 16 + lr) * PSTR + k * 32 + lg * 8];
#pragma unroll
                for (int nt = 0; nt < 8; ++nt) {
                    acc[0][nt] = __builtin_amdgcn_mfma_f32_16x16x32_bf16(a0, bfr[nt], acc[0][nt], 0, 0, 0);
                    acc[1][nt] = __builtin_amdgcn_mfma_f32_16x16x32_bf16(a1, bfr[nt], acc[1][nt], 0, 0, 0);
                    acc[2][nt] = __builtin_amdgcn_mfma_f32_16x16x32_bf16(a2, bfr[nt], acc[2][nt], 0, 0, 0);
                    acc[3][nt] = __builtin_amdgcn_mfma_f32_16x16x32_bf16(a3, bfr[nt], acc[3][nt], 0, 0, 0);
                }
            }
            __builtin_amdgcn_s_setprio(0);
        } else if (chunk < 3) {
            // ---- stage A(c+1) by waves 4-7, overlapping MFMA(c) ----
            const int c0n = c0 + 32;
            const float* xp = x + ((size_t)(b * CC + c0n + cA2) * HH) * WW + colh;
            __bf16* yw = yrA2 + cA2 * YSTR + colh;
#pragma unroll
            for (int g = 0; g < 8; ++g) {
                float4 v[4];
#pragma unroll
                for (int r = 0; r < 4; ++r) {
                    float4 t = {0.f, 0.f, 0.f, 0.f};
                    if (rvA2[r]) t = *(const float4*)(xp + (size_t)hrA2[r] * WW + g * 4);
                    v[r] = t;
                }
#pragma unroll
                for (int kh = 0; kh < 3; ++kh) {
                    bf16x4 t;
                    t[0] = (__bf16)(v[kh].x + fhA2 * (v[kh + 1].x - v[kh].x));
                    t[1] = (__bf16)(v[kh].y + fhA2 * (v[kh + 1].y - v[kh].y));
                    t[2] = (__bf16)(v[kh].z + fhA2 * (v[kh + 1].z - v[kh].z));
                    t[3] = (__bf16)(v[kh].w + fhA2 * (v[kh + 1].w - v[kh].w));
                    *(bf16x4*)(yw + kh * 64 + g * 4) = t;
                }
            }
        }
        __syncthreads();   // barA: MFMA pT reads drained; yr(c+1) complete
    }

    // ---- epilogue: waves 0-3 store (C/D: col=lane&15, row=(lane>>4)*4+reg) ----
    if (wv < 4) {
#pragma unroll
        for (int ot = 0; ot < 4; ++ot) {
#pragma unroll
            for (int r = 0; r < 4; ++r) {
                int o = o0 + ot * 16 + lg * 4 + r;
                float bv = bias[o];
#pragma unroll
                for (int nt = 0; nt < 8; ++nt) {
                    int pi = nt >> 1;
                    int qc = (nt & 1) * 16 + lr;
                    out[(((size_t)b * OO + o) * OHH + p0 + pi) * OWW + qc] = acc[ot][nt][r] + bv;
                }
            }
        }
    }
}

// ---- fp32 fallback (no workspace) ----
__global__ __launch_bounds__(256)
void conv_fallback_kernel(const float* __restrict__ x, const float* __restrict__ w,
                          const float* __restrict__ bias, const float* __restrict__ shp,
                          const float* __restrict__ swp, float* __restrict__ out) {
    __shared__ __align__(16) float xr[4][WW];
    __shared__ __align__(16) float patch[9][OWW];
    const int tid = threadIdx.x;
    const int p = blockIdx.y;
    const int b = blockIdx.x;
    const float sh = shp[0];
    const float sw = swp[0];
    const float hpos = (float)p * sh - 1.0f;
    const float hbf  = floorf(hpos);
    const float fh   = hpos - hbf;
    const int   hb   = (int)hbf;
    const int og = tid & 63;
    const int qg = tid >> 6;
    const int o0 = og * 4;
    const int q0 = qg * 8;
    const int rr   = tid >> 6;
    const int colc = tid & 63;
    const int rowg = hb + rr;
    const bool rv = (rowg >= 0) && (rowg < HH);
    float acc[4][8];
#pragma unroll
    for (int i = 0; i < 4; ++i)
#pragma unroll
        for (int j = 0; j < 8; ++j) acc[i][j] = 0.0f;
    for (int c = 0; c < CC; ++c) {
        float vv = 0.0f;
        if (rv) vv = x[(((size_t)b * CC + c) * HH + rowg) * WW + colc];
        xr[rr][colc] = vv;
        __syncthreads();
        for (int it = tid; it < 9 * OWW; it += 256) {
            int k = it >> 5; int q = it & 31;
            int kh = k / 3;  int kw = k - kh * 3;
            float wpos = (float)q * sw - 1.0f + (float)kw;
            float wbf = floorf(wpos);
            float fwl = wpos - wbf;
            int wb = (int)wbf;
            float x00 = 0, x01 = 0, x10 = 0, x11 = 0;
            if (wb >= 0 && wb < WW)         { x00 = xr[kh][wb];     x10 = xr[kh + 1][wb]; }
            if (wb + 1 >= 0 && wb + 1 < WW) { x01 = xr[kh][wb + 1]; x11 = xr[kh + 1][wb + 1]; }
            float top = x00 * (1.0f - fwl) + x01 * fwl;
            float bot = x10 * (1.0f - fwl) + x11 * fwl;
            patch[k][q] = top * (1.0f - fh) + bot * fh;
        }
        __syncthreads();
        const float4* pv = (const float4*)&patch[0][0];
#pragma unroll
        for (int k = 0; k < 9; ++k) {
            const float* wb_ = w + (size_t)o0 * (CC * 9) + c * 9 + k;
            float wvv[4] = {wb_[0], wb_[1 * CC * 9], wb_[2 * CC * 9], wb_[3 * CC * 9]};
            float4 pa = pv[k * 8 + (q0 >> 2)];
            float4 pb = pv[k * 8 + (q0 >> 2) + 1];
#pragma unroll
            for (int oo2 = 0; oo2 < 4; ++oo2) {
                acc[oo2][0] += wvv[oo2] * pa.x; acc[oo2][1] += wvv[oo2] * pa.y;
                acc[oo2][2] += wvv[oo2] * pa.z; acc[oo2][3] += wvv[oo2] * pa.w;
                acc[oo2][4] += wvv[oo2] * pb.x; acc[oo2][5] += wvv[oo2] * pb.y;
                acc[oo2][6] += wvv[oo2] * pb.z; acc[oo2][7] += wvv[oo2] * pb.w;
            }
        }
    }
    float4 bv = ((const float4*)bias)[og];
    float bvv[4] = {bv.x, bv.y, bv.z, bv.w};
#pragma unroll
    for (int oo2 = 0; oo2 < 4; ++oo2) {
        size_t off = (((size_t)b * OO + o0 + oo2) * OHH + p) * OWW + q0;
        float4 r0, r1;
        r0.x = acc[oo2][0] + bvv[oo2]; r0.y = acc[oo2][1] + bvv[oo2];
        r0.z = acc[oo2][2] + bvv[oo2]; r0.w = acc[oo2][3] + bvv[oo2];
        r1.x = acc[oo2][4] + bvv[oo2]; r1.y = acc[oo2][5] + bvv[oo2];
        r1.z = acc[oo2][6] + bvv[oo2]; r1.w = acc[oo2][7] + bvv[oo2];
        *(float4*)(out + off)     = r0;
        *(float4*)(out + off + 4) = r1;
    }
}

extern "C" void kernel_launch(void* const* d_in, const int* in_sizes, int n_in,
                              void* d_out, int out_size, void* d_ws, size_t ws_size,
                              hipStream_t stream) {
    const float* x    = (const float*)d_in[0];
    const float* w    = (const float*)d_in[1];
    const float* bias = (const float*)d_in[2];
    const float* shp  = (const float*)d_in[3];
    const float* swp  = (const float*)d_in[4];
    float* out = (float*)d_out;

    const size_t wt_bytes = (size_t)OO * 9 * CC * sizeof(__bf16);   // 576 KB
    if (ws_size >= wt_bytes) {
        __bf16* wtp = (__bf16*)d_ws;
        int n = OO * 9 * CC;
        wtrans_bf16_kernel<<<(n + 255) / 256, 256, 0, stream>>>(w, wtp);
        dim3 grid(BB, OHH / 4);
        conv_mfma_kernel<<<grid, 512, 0, stream>>>(x, wtp, bias, shp, swp, out);
    } else {
        dim3 grid(BB, OHH);
        conv_fallback_kernel<<<grid, 256, 0, stream>>>(x, w, bias, shp, swp, out);
    }
}

// Round 20
// 54.799 us; speedup vs baseline: 1.2753x; 1.1958x over previous
//
#include <hip/hip_runtime.h>
#include <cstddef>

#define BB  32
#define CC  128
#define HH  64
#define WW  64
#define OO  256
#define OHH 32
#define OWW 32
#define YSTR 196            // yr row stride (bf16 elems)
#define PSTR 296            // pT row stride; 592B rows, 16B-aligned
#define ROWE (32 * YSTR)    // 6272 elems per yr(p) buffer

typedef __bf16 bf16x8 __attribute__((ext_vector_type(8)));
typedef __bf16 bf16x4 __attribute__((ext_vector_type(4)));
typedef float  f32x4  __attribute__((ext_vector_type(4)));

// ---- weight transform: w[o][c][3][3] f32 -> wt[o][k][c] bf16 (k = kh*3+kw) ----
__global__ void wtrans_bf16_kernel(const float* __restrict__ w, __bf16* __restrict__ wt) {
    int idx = blockIdx.x * 256 + threadIdx.x;          // (o*9 + k)*128 + c
    if (idx >= OO * 9 * CC) return;
    int c    = idx & 127;
    int rest = idx >> 7;
    int k    = rest % 9;
    int o    = rest / 9;
    wt[idx] = (__bf16)w[((size_t)o * CC + c) * 9 + k];
}

// ---- fused bilinear-im2col + bf16 MFMA; block = (b, 4 p-rows), N=128 ----
// grid (b=32, pp=8) = 256 blocks = 1/CU. 512 thr = 8 waves; LDS 126KB.
// FINAL (R14 structure, best measured 55.1us): N=128/block minimizes wt(A)
// traffic per output — the only lever that moved the wall (R11: 86->55).
// Wave = 32o x 128n (A via slow L2 minimized, B via fast LDS). Simple
// 2-barrier loop: pipelining (R16), hoisting (R17), producer-consumer (R18),
// and role-split (R19) were all neutral-or-negative against this structure.
__global__ __launch_bounds__(512, 2)
void conv_mfma_kernel(const float* __restrict__ x, const __bf16* __restrict__ wt,
                      const float* __restrict__ bias, const float* __restrict__ shp,
                      const float* __restrict__ swp, float* __restrict__ out) {
    __shared__ __align__(16) __bf16 yrbuf[4 + 4 * ROWE];   // 4 p-rows + front pad
    __shared__ __align__(16) __bf16 pT[128 * PSTR];        // B operand: row = pi*32+q

    const int tid = threadIdx.x;
    const int b   = blockIdx.x;
    const int p0  = blockIdx.y * 4;
    const float sh = shp[0];
    const float sw = swp[0];

    // per-p row geometry (4 rows of this block)
    float fh_[4];
    int   hb_[4];
    bool  oob[4];
#pragma unroll
    for (int pi = 0; pi < 4; ++pi) {
        float hpos = (float)(p0 + pi) * sh - 1.0f;
        float hbf  = floorf(hpos);
        fh_[pi] = hpos - hbf;
        hb_[pi] = (int)hbf;
        oob[pi] = (hb_[pi] >= HH || hb_[pi] <= -4);
    }

    // ---- bias-only fast path: all 4 rows fully OOB ----
    if (oob[0] && oob[1] && oob[2] && oob[3]) {
#pragma unroll
        for (int j = 0; j < 16; ++j) {
            int fi = j * 512 + tid;        // 8192 float4 = 256 o x 4 p x 8
            int o  = fi >> 5;
            int rem = fi & 31;
            int pi = rem >> 3;
            int qf = rem & 7;
            float bv = bias[o];
            float4 r; r.x = bv; r.y = bv; r.z = bv; r.w = bv;
            *(float4*)(out + (((size_t)b * OO + o) * OHH + p0 + pi) * OWW + qf * 4) = r;
        }
        return;
    }
    // (mixed OOB rows fall through: masked loads -> zero patch -> bias)

    // ---- stage-A ownership: 128 threads per p-row; (c, 16-col group) ----
    const int piA = tid >> 7;             // 0..3
    const int t7  = tid & 127;
    const int cA  = t7 >> 2;              // 0..31
    const int cg0 = (t7 & 3) * 16;        // col group start: 0,16,32,48
    const float fhA = fh_[piA];
    int  hrA[4];
    bool rvA[4];
#pragma unroll
    for (int r = 0; r < 4; ++r) {
        hrA[r] = hb_[piA] + r;
        rvA[r] = (hrA[r] >= 0) && (hrA[r] < HH);
    }
    __bf16* yrA = yrbuf + 4 + piA * ROWE;

    // ---- stage-B ownership: (pi, q, 8 channels in 2 groups of 4) ----
    const int piB = tid >> 7;             // 0..3
    const int qB  = (tid >> 2) & 31;      // 0..31
    const int cB  = (tid & 3) * 8;        // 0,8,16,24
    const float wposB = (float)qB * sw - 1.0f;
    const float wbfB  = floorf(wposB);
    const float fw    = wposB - wbfB;
    const int   wbq   = (int)wbfB;
    const int   wba   = min(wbq & ~3, 60);
    const int   e     = wbq - wba;
    const bool  g1 = e >= 1, g2 = e >= 2, g3 = e >= 3;
    bool mv[4];
#pragma unroll
    for (int j = 0; j < 4; ++j) mv[j] = ((unsigned)(wbq + j) < (unsigned)WW);
    const __bf16* yrB = yrbuf + 4 + piB * ROWE;
    __bf16* pqRow = pT + (piB * 32 + qB) * PSTR;

    // ---- MFMA ownership: wave -> 32 o; all 128 n-rows ----
    const int wv = tid >> 6;
    const int l  = tid & 63;
    const int lr = l & 15;
    const int lg = l >> 4;
    const int o0 = wv * 32;

    f32x4 acc[2][8];
#pragma unroll
    for (int ot = 0; ot < 2; ++ot)
#pragma unroll
        for (int nt = 0; nt < 8; ++nt) acc[ot][nt] = (f32x4)0.0f;

    if (tid < 4) yrbuf[tid] = (__bf16)0.0f;   // zero front pad

    for (int chunk = 0; chunk < 4; ++chunk) {
        const int c0 = chunk * 32;

        // ---- stage A: load 4 x-rows x 16 cols, row-interp, write yr[piA] ----
        {
            const float* xp = x + ((size_t)(b * CC + c0 + cA) * HH) * WW;
            float4 v[4][4];   // [row][col4]
#pragma unroll
            for (int r = 0; r < 4; ++r) {
                if (rvA[r]) {
                    const float* rp = xp + (size_t)hrA[r] * WW + cg0;
#pragma unroll
                    for (int g = 0; g < 4; ++g) v[r][g] = *(const float4*)(rp + g * 4);
                } else {
#pragma unroll
                    for (int g = 0; g < 4; ++g) { v[r][g].x = 0.f; v[r][g].y = 0.f; v[r][g].z = 0.f; v[r][g].w = 0.f; }
                }
            }
            __bf16* yw = yrA + cA * YSTR + cg0;
#pragma unroll
            for (int kh = 0; kh < 3; ++kh) {
#pragma unroll
                for (int g = 0; g < 4; ++g) {
                    bf16x4 t;
                    t[0] = (__bf16)(v[kh][g].x + fhA * (v[kh + 1][g].x - v[kh][g].x));
                    t[1] = (__bf16)(v[kh][g].y + fhA * (v[kh + 1][g].y - v[kh][g].y));
                    t[2] = (__bf16)(v[kh][g].z + fhA * (v[kh + 1][g].z - v[kh][g].z));
                    t[3] = (__bf16)(v[kh][g].w + fhA * (v[kh + 1][g].w - v[kh][g].w));
                    *(bf16x4*)(yw + kh * 64 + g * 4) = t;
                }
            }
        }
        __syncthreads();   // barA: yr ready; prev chunk's pT MFMA-reads drained

        // ---- stage B: col-interp yr -> pT (2 groups of 4 channels) ----
#pragma unroll
        for (int g = 0; g < 2; ++g) {
            const int cc0 = cB + g * 4;
            float tv[3][3][4];   // [kh][kw][ci]
#pragma unroll
            for (int ci = 0; ci < 4; ++ci) {
                const __bf16* yc = yrB + (cc0 + ci) * YSTR + wba;
#pragma unroll
                for (int kh = 0; kh < 3; ++kh) {
                    bf16x4 a  = *(const bf16x4*)(yc + kh * 64);
                    bf16x4 bq = *(const bf16x4*)(yc + kh * 64 + 4);
                    float v0 = (float)a[0], v1 = (float)a[1], v2 = (float)a[2], v3 = (float)a[3];
                    float v4 = (float)bq[0], v5 = (float)bq[1], v6 = (float)bq[2];
                    float s0 = g1 ? v1 : v0; s0 = g2 ? v2 : s0; s0 = g3 ? v3 : s0;
                    float s1 = g1 ? v2 : v1; s1 = g2 ? v3 : s1; s1 = g3 ? v4 : s1;
                    float s2 = g1 ? v3 : v2; s2 = g2 ? v4 : s2; s2 = g3 ? v5 : s2;
                    float s3 = g1 ? v4 : v3; s3 = g2 ? v5 : s3; s3 = g3 ? v6 : s3;
                    s0 = mv[0] ? s0 : 0.0f;
                    s1 = mv[1] ? s1 : 0.0f;
                    s2 = mv[2] ? s2 : 0.0f;
                    s3 = mv[3] ? s3 : 0.0f;
                    tv[kh][0][ci] = s0 + fw * (s1 - s0);
                    tv[kh][1][ci] = s1 + fw * (s2 - s1);
                    tv[kh][2][ci] = s2 + fw * (s3 - s2);
                }
            }
#pragma unroll
            for (int kh = 0; kh < 3; ++kh)
#pragma unroll
                for (int kw = 0; kw < 3; ++kw) {
                    bf16x4 pr;
                    pr[0] = (__bf16)tv[kh][kw][0];
                    pr[1] = (__bf16)tv[kh][kw][1];
                    pr[2] = (__bf16)tv[kh][kw][2];
                    pr[3] = (__bf16)tv[kh][kw][3];
                    *(bf16x4*)(pqRow + (kh * 3 + kw) * 32 + cc0) = pr;
                }
        }
        __syncthreads();   // barB: pT ready; yr reads drained

        // ---- MFMA: 9 taps x (2 o-tiles x 8 n-tiles); A in-loop (2 loads/tap) ----
        __builtin_amdgcn_s_setprio(1);
#pragma unroll
        for (int k = 0; k < 9; ++k) {
            const __bf16* wp = wt + ((size_t)(o0 + lr) * 9 + k) * CC + c0 + lg * 8;
            bf16x8 a0 = *(const bf16x8*)(wp);
            bf16x8 a1 = *(const bf16x8*)(wp + (size_t)16 * 9 * CC);
            bf16x8 bfr[8];
#pragma unroll
            for (int nt = 0; nt < 8; ++nt)
                bfr[nt] = *(const bf16x8*)&pT[(nt * 16 + lr) * PSTR + k * 32 + lg * 8];
#pragma unroll
            for (int nt = 0; nt < 8; ++nt) {
                acc[0][nt] = __builtin_amdgcn_mfma_f32_16x16x32_bf16(a0, bfr[nt], acc[0][nt], 0, 0, 0);
                acc[1][nt] = __builtin_amdgcn_mfma_f32_16x16x32_bf16(a1, bfr[nt], acc[1][nt], 0, 0, 0);
            }
        }
        __builtin_amdgcn_s_setprio(0);
        // pT overwrite fenced by next barA; yr overwrite fenced by barB.
    }

    // ---- epilogue: + bias, store (C/D: col=lane&15, row=(lane>>4)*4+reg) ----
#pragma unroll
    for (int ot = 0; ot < 2; ++ot) {
#pragma unroll
        for (int r = 0; r < 4; ++r) {
            int o = o0 + ot * 16 + lg * 4 + r;
            float bv = bias[o];
#pragma unroll
            for (int nt = 0; nt < 8; ++nt) {
                int pi = nt >> 1;
                int qc = (nt & 1) * 16 + lr;
                out[(((size_t)b * OO + o) * OHH + p0 + pi) * OWW + qc] = acc[ot][nt][r] + bv;
            }
        }
    }
}

// ---- fp32 fallback (no workspace) ----
__global__ __launch_bounds__(256)
void conv_fallback_kernel(const float* __restrict__ x, const float* __restrict__ w,
                          const float* __restrict__ bias, const float* __restrict__ shp,
                          const float* __restrict__ swp, float* __restrict__ out) {
    __shared__ __align__(16) float xr[4][WW];
    __shared__ __align__(16) float patch[9][OWW];
    const int tid = threadIdx.x;
    const int p = blockIdx.y;
    const int b = blockIdx.x;
    const float sh = shp[0];
    const float sw = swp[0];
    const float hpos = (float)p * sh - 1.0f;
    const float hbf  = floorf(hpos);
    const float fh   = hpos - hbf;
    const int   hb   = (int)hbf;
    const int og = tid & 63;
    const int qg = tid >> 6;
    const int o0 = og * 4;
    const int q0 = qg * 8;
    const int rr   = tid >> 6;
    const int colc = tid & 63;
    const int rowg = hb + rr;
    const bool rv = (rowg >= 0) && (rowg < HH);
    float acc[4][8];
#pragma unroll
    for (int i = 0; i < 4; ++i)
#pragma unroll
        for (int j = 0; j < 8; ++j) acc[i][j] = 0.0f;
    for (int c = 0; c < CC; ++c) {
        float vv = 0.0f;
        if (rv) vv = x[(((size_t)b * CC + c) * HH + rowg) * WW + colc];
        xr[rr][colc] = vv;
        __syncthreads();
        for (int it = tid; it < 9 * OWW; it += 256) {
            int k = it >> 5; int q = it & 31;
            int kh = k / 3;  int kw = k - kh * 3;
            float wpos = (float)q * sw - 1.0f + (float)kw;
            float wbf = floorf(wpos);
            float fwl = wpos - wbf;
            int wb = (int)wbf;
            float x00 = 0, x01 = 0, x10 = 0, x11 = 0;
            if (wb >= 0 && wb < WW)         { x00 = xr[kh][wb];     x10 = xr[kh + 1][wb]; }
            if (wb + 1 >= 0 && wb + 1 < WW) { x01 = xr[kh][wb + 1]; x11 = xr[kh + 1][wb + 1]; }
            float top = x00 * (1.0f - fwl) + x01 * fwl;
            float bot = x10 * (1.0f - fwl) + x11 * fwl;
            patch[k][q] = top * (1.0f - fh) + bot * fh;
        }
        __syncthreads();
        const float4* pv = (const float4*)&patch[0][0];
#pragma unroll
        for (int k = 0; k < 9; ++k) {
            const float* wb_ = w + (size_t)o0 * (CC * 9) + c * 9 + k;
            float wvv[4] = {wb_[0], wb_[1 * CC * 9], wb_[2 * CC * 9], wb_[3 * CC * 9]};
            float4 pa = pv[k * 8 + (q0 >> 2)];
            float4 pb = pv[k * 8 + (q0 >> 2) + 1];
#pragma unroll
            for (int oo2 = 0; oo2 < 4; ++oo2) {
                acc[oo2][0] += wvv[oo2] * pa.x; acc[oo2][1] += wvv[oo2] * pa.y;
                acc[oo2][2] += wvv[oo2] * pa.z; acc[oo2][3] += wvv[oo2] * pa.w;
                acc[oo2][4] += wvv[oo2] * pb.x; acc[oo2][5] += wvv[oo2] * pb.y;
                acc[oo2][6] += wvv[oo2] * pb.z; acc[oo2][7] += wvv[oo2] * pb.w;
            }
        }
    }
    float4 bv = ((const float4*)bias)[og];
    float bvv[4] = {bv.x, bv.y, bv.z, bv.w};
#pragma unroll
    for (int oo2 = 0; oo2 < 4; ++oo2) {
        size_t off = (((size_t)b * OO + o0 + oo2) * OHH + p) * OWW + q0;
        float4 r0, r1;
        r0.x = acc[oo2][0] + bvv[oo2]; r0.y = acc[oo2][1] + bvv[oo2];
        r0.z = acc[oo2][2] + bvv[oo2]; r0.w = acc[oo2][3] + bvv[oo2];
        r1.x = acc[oo2][4] + bvv[oo2]; r1.y = acc[oo2][5] + bvv[oo2];
        r1.z = acc[oo2][6] + bvv[oo2]; r1.w = acc[oo2][7] + bvv[oo2];
        *(float4*)(out + off)     = r0;
        *(float4*)(out + off + 4) = r1;
    }
}

extern "C" void kernel_launch(void* const* d_in, const int* in_sizes, int n_in,
                              void* d_out, int out_size, void* d_ws, size_t ws_size,
                              hipStream_t stream) {
    const float* x    = (const float*)d_in[0];
    const float* w    = (const float*)d_in[1];
    const float* bias = (const float*)d_in[2];
    const float* shp  = (const float*)d_in[3];
    const float* swp  = (const float*)d_in[4];
    float* out = (float*)d_out;

    const size_t wt_bytes = (size_t)OO * 9 * CC * sizeof(__bf16);   // 576 KB
    if (ws_size >= wt_bytes) {
        __bf16* wtp = (__bf16*)d_ws;
        int n = OO * 9 * CC;
        wtrans_bf16_kernel<<<(n + 255) / 256, 256, 0, stream>>>(w, wtp);
        dim3 grid(BB, OHH / 4);
        conv_mfma_kernel<<<grid, 512, 0, stream>>>(x, wtp, bias, shp, swp, out);
    } else {
        dim3 grid(BB, OHH);
        conv_fallback_kernel<<<grid, 256, 0, stream>>>(x, w, bias, shp, swp, out);
    }
}